// Round 27
// baseline (172.650 us; speedup 1.0000x reference)
//
#include <hip/hip_runtime.h>
#include <hip/hip_bf16.h>

// ---------- types / helpers ----------
typedef __attribute__((ext_vector_type(4))) float f32x4;   // MFMA C/D frag
typedef __attribute__((ext_vector_type(4))) int   int4v;   // one 16B load
typedef __attribute__((ext_vector_type(8))) int   int8v;   // K=128 fp8 A/B frag (32B)

// float -> OCP e4m3fn byte (cold path: weight prep only)
__device__ __forceinline__ unsigned char f2fp8(float f) {
    unsigned char s = (__float_as_uint(f) >> 24) & 0x80;
    float a = fabsf(f);
    if (a >= 448.f) return s | 0x7E;
    if (a < 0.015625f) {                       // subnormal: step 2^-9
        int q = (int)(a * 512.0f + 0.5f);
        return s | (unsigned char)q;
    }
    unsigned int u = __float_as_uint(a);
    u += 0x0007FFFF + ((u >> 20) & 1);         // RNE to 3 mantissa bits (carry-safe)
    int e8 = (int)((u >> 23) & 0xFF) - 120;    // -127+7
    if (e8 >= 16) return s | 0x7E;
    return s | (unsigned char)((e8 << 3) | ((u >> 20) & 7));
}
__device__ __forceinline__ void gload_lds16(const void* g, void* l) {
    // async global->LDS, 16B/lane; LDS dest = wave-uniform base + lane*16 (linear!)
    // global SOURCE is per-lane -> gathered (indexed-row) staging is legal.
    __builtin_amdgcn_global_load_lds((const __attribute__((address_space(1))) void*)g,
                                     (__attribute__((address_space(3))) void*)l, 16, 0, 0);
}

// ---------- constants ----------
#define BATCH 256
#define CHAN  768
#define HW    196
#define SPS   196
#define HID   512
#define MROWS 50176   // BATCH*SPS
#define K1    1536    // 2*CHAN
#define WSCL  64.0f           // weights pre-scaled by 64 (e4m3 subnormal dodge)
#define WINV  0.015625f       // 1/64 applied after each GEMM
#define SC1   0x7F7F7F7F      // E8M0 scale 1.0 in every byte
#define GPITCH 198            // xpose8 LDS row pitch (floats)

// R27 = R26 (proven 145.7us) with prep_weights FOLDED into xpose8's grid
// (24 extra blocks, by >= BATCH, block-uniform branch) -> 3 kernels total.
// All compute paths byte-identical to R24/R26.

// ---------- xpose8 (+weight prep blocks): x -> x8 fp8; pidx; deltaxy; pred=b3 ----------
__global__ __launch_bounds__(512) void xpose8(const float* __restrict__ x,
                                              const int* __restrict__ pxs,
                                              const int* __restrict__ pys,
                                              const float* __restrict__ b3,
                                              const float* __restrict__ W1,
                                              const float* __restrict__ W2,
                                              unsigned char* __restrict__ W1t,
                                              unsigned char* __restrict__ W2t,
                                              unsigned char* __restrict__ x8,
                                              int* __restrict__ pidx,
                                              float* __restrict__ out) {
    __shared__ float lds[64 * GPITCH];   // 50,688 B -> 3 blocks/CU
    int chunk = blockIdx.x;           // 0..11 (64-channel chunk)
    int b     = blockIdx.y;           // 0..BATCH+1
    if (b >= BATCH) {                 // ---- weight-prep blocks (24 x 512 thr) ----
        const int G1 = K1 * (HID / 4);               // 196,608 W1 float4-groups
        const int GT = G1 + HID * (HID / 4);         // + 65,536 W2 groups = 262,144
        int wblk = chunk + 12 * (b - BATCH);         // 0..23
        for (int idx = wblk * 512 + threadIdx.x; idx < GT; idx += 24 * 512) {
            if (idx < G1) {
                int k = idx >> 7, g = idx & 127;     // 128 groups per k-row
                float4 v = *(const float4*)(W1 + (size_t)k * HID + g * 4);   // coalesced
                W1t[(size_t)(g * 4 + 0) * K1 + k] = f2fp8(v.x * WSCL);
                W1t[(size_t)(g * 4 + 1) * K1 + k] = f2fp8(v.y * WSCL);
                W1t[(size_t)(g * 4 + 2) * K1 + k] = f2fp8(v.z * WSCL);
                W1t[(size_t)(g * 4 + 3) * K1 + k] = f2fp8(v.w * WSCL);
            } else {
                int i = idx - G1;
                int k = i >> 7, g = i & 127;
                float4 v = *(const float4*)(W2 + (size_t)k * HID + g * 4);
                W2t[(size_t)(g * 4 + 0) * HID + k] = f2fp8(v.x * WSCL);
                W2t[(size_t)(g * 4 + 1) * HID + k] = f2fp8(v.y * WSCL);
                W2t[(size_t)(g * 4 + 2) * HID + k] = f2fp8(v.z * WSCL);
                W2t[(size_t)(g * 4 + 3) * HID + k] = f2fp8(v.w * WSCL);
            }
        }
        return;                       // block-uniform: no barrier divergence
    }
    int c0 = chunk * 64;
    const float4* xb4 = (const float4*)(x + ((size_t)b * CHAN + c0) * HW);  // 16B-aligned
    for (int vt = threadIdx.x; vt < 64 * 49; vt += 512) {    // 64 rows x 49 float4
        float4 v = xb4[vt];
        int j = vt / 49, p4 = vt - j * 49;
        float* dst = &lds[j * GPITCH + p4 * 4];              // 8B-aligned (GPITCH even)
        *(float2*)(dst + 0) = make_float2(v.x, v.y);
        *(float2*)(dst + 2) = make_float2(v.z, v.w);
    }
    if (chunk == 0) {                 // per-batch: pred=b3, deltaxy, pidx
        float b30 = b3[0], b31 = b3[1];
        for (int i = threadIdx.x; i < SPS * 2; i += 512) {
            int idx = b * SPS * 2 + i;
            out[idx] = (i & 1) ? b31 : b30;                  // pred init (GEMM2 atomics add)
            out[MROWS * 2 + idx] = (float)(pxs[idx] - pys[idx]) + 13.0f;  // (H-1)=13
        }
        for (int s = threadIdx.x; s < SPS; s += 512) {
            int base = (b * SPS + s) * 2;
            int ix = pxs[base] * 14 + pxs[base + 1];
            int iy = pys[base] * 14 + pys[base + 1];
            pidx[(b * SPS + s) * 2 + 0] = b * HW + ix;
            pidx[(b * SPS + s) * 2 + 1] = b * HW + iy;
        }
    }
    __syncthreads();
    int wid = threadIdx.x >> 6, lane = threadIdx.x & 63;
    int g = lane >> 4;                // pos-offset within the 4-pos pack
    int cq = (lane & 15) * 4;         // channel quad
    const float* lx = lds + cq * GPITCH;
    // p = 4*wid + 32k + g covers 0..195 exactly once
    for (int pb = wid * 4; pb < HW; pb += 32) {
        int p = pb + g;
        unsigned int u = 0;
        u = __builtin_amdgcn_cvt_pk_fp8_f32(lx[p],              lx[GPITCH + p],     u, false);
        u = __builtin_amdgcn_cvt_pk_fp8_f32(lx[2 * GPITCH + p], lx[3 * GPITCH + p], u, true);
        *(unsigned int*)(x8 + ((size_t)b * HW + p) * CHAN + c0 + cq) = u;  // 64B/16-lane grp
    }
}

// ---------- 64x256 MX-fp8 GEMM, spill-free; optional gathered-A (R24, proven) ----------
// C = relu((A @ Bt^T)/64 + bias) -> fp8 (predMode=0), or pred-fold (predMode=1).
// pidx != nullptr: A rows are gathered from x8 (row pidx[r*2+(kt>=6)], 768B rows).
// Grid 1-D: nHalf = bid&1 (cols 0-255 / 256-511), mChunk = bid>>1.
__global__ __launch_bounds__(512, 2)
void gemm64(const unsigned char* __restrict__ A,
            const unsigned char* __restrict__ Bt,
            const float* __restrict__ bias,
            unsigned char* __restrict__ C,
            const float* __restrict__ W3,
            float* __restrict__ out,
            const int* __restrict__ pidx,
            int Kd, int predMode) {
    extern __shared__ char smem[];    // 81920 B: [A0 8K | A1 8K | B0 32K | B1 32K]
    const int t = threadIdx.x;
    const int wid = t >> 6, lane = t & 63;
    const int lr = lane & 15, lk = lane >> 4;
    const int mBase = (blockIdx.x >> 1) * 64;
    const int nBase = (blockIdx.x & 1) * 256;
    const int nK = Kd >> 7;           // BK=128
    f32x4 acc[4][2] = {};             // 32 regs; live ~90 <= 128-reg budget: no spill

    // gathered-A row ids for this thread's fixed staging row (t>>3), L2-hot
    int prx = 0, pry = 0;
    if (pidx) {
        int gr = mBase + (t >> 3);
        prx = pidx[gr * 2 + 0];
        pry = pidx[gr * 2 + 1];
    }

    auto stage = [&](int buf, int kt) {
        char* Ab = smem + buf * 8192;
        char* Bb = smem + 16384 + buf * 32768;
        {                                         // A: 512 units = 64 rows x 128B
            int row = t >> 3, cs = (t & 7) ^ (row & 7);
            const unsigned char* asrc;
            if (pidx) {                           // gathered from x8 (768B rows)
                int srcRow = (kt < 6) ? prx : pry;
                int kk = (kt < 6) ? kt : kt - 6;
                asrc = A + (size_t)srcRow * CHAN + kk * 128 + cs * 16;
            } else {
                asrc = A + (size_t)(mBase + row) * Kd + kt * 128 + cs * 16;
            }
            gload_lds16(asrc, Ab + t * 16);
        }
        #pragma unroll
        for (int i = 0; i < 4; ++i) {             // B: 2048 units = 256 rows x 128B
            int lin = i * 512 + t, row = lin >> 3, cs = (lin & 7) ^ (row & 7);
            gload_lds16(Bt + (size_t)(nBase + row) * Kd + kt * 128 + cs * 16,
                        Bb + lin * 16);
        }
    };
    auto frag128 = [&](const char* rowp, int r) -> int8v {   // swizzled 32B frag, 128B row
        union { int4v h[2]; int8v v; } u;
        u.h[0] = *(const int4v*)(rowp + (((2 * lk + 0) ^ (r & 7)) * 16));
        u.h[1] = *(const int4v*)(rowp + (((2 * lk + 1) ^ (r & 7)) * 16));
        return u.v;
    };
    auto compute = [&](int buf) {
        const char* Ab = smem + buf * 8192;
        const char* Bb = smem + 16384 + buf * 32768;
        int8v af[4];
        #pragma unroll
        for (int m = 0; m < 4; ++m) {             // all waves share rows 0..63 (broadcast)
            int r = m * 16 + lr;
            af[m] = frag128(Ab + r * 128, r);
        }
        #pragma unroll
        for (int n = 0; n < 2; ++n) {             // one B frag live at a time
            int r = wid * 32 + n * 16 + lr;
            int8v bf = frag128(Bb + r * 128, r);
            #pragma unroll
            for (int m = 0; m < 4; ++m)
                acc[m][n] = __builtin_amdgcn_mfma_scale_f32_16x16x128_f8f6f4(
                    af[m], bf, acc[m][n], 0, 0, 0, SC1, 0, SC1);
        }
    };

    stage(0, 0);
    __syncthreads();
    int cur = 0;
    for (int kt = 0; kt < nK; ++kt) {
        if (kt + 1 < nK) stage(cur ^ 1, kt + 1);   // flies under compute(kt)
        compute(cur);
        __syncthreads();
        cur ^= 1;
    }

    if (!predMode) {
        // h1 = relu(acc/64 + b1) -> fp8 global.  C row=lk*4+j, col=lane&15 (verified)
        #pragma unroll
        for (int n = 0; n < 2; ++n) {
            int c = nBase + wid * 32 + n * 16 + lr;
            float bv = bias[c];
            #pragma unroll
            for (int m = 0; m < 4; ++m) {
                int r0 = mBase + m * 16 + lk * 4;
                float v0 = fmaxf(acc[m][n][0] * WINV + bv, 0.f);
                float v1 = fmaxf(acc[m][n][1] * WINV + bv, 0.f);
                float v2 = fmaxf(acc[m][n][2] * WINV + bv, 0.f);
                float v3 = fmaxf(acc[m][n][3] * WINV + bv, 0.f);
                unsigned int u = __builtin_amdgcn_cvt_pk_fp8_f32(v0, v1, 0u, false);
                u = __builtin_amdgcn_cvt_pk_fp8_f32(v2, v3, u, true);
                #pragma unroll
                for (int j = 0; j < 4; ++j)
                    C[(size_t)(r0 + j) * HID + c] = (unsigned char)((u >> (8 * j)) & 0xff);
            }
        }
    } else {
        // pred fold: pred[r] += sum_c relu(acc/64+b2)[r][c] * W3[c][:]
        float* red = (float*)smem;    // [64][17] f32 = 4.4KB over dead A0/A1
        float bv2[2], w30[2], w31[2];
        #pragma unroll
        for (int n = 0; n < 2; ++n) {
            int c = nBase + wid * 32 + n * 16 + lr;
            bv2[n] = bias[c];
            w30[n] = W3[c * 2];
            w31[n] = W3[c * 2 + 1];
        }
        __syncthreads();              // all LDS reads of A/B done before red overwrite
        #pragma unroll
        for (int m = 0; m < 4; ++m) {
            #pragma unroll
            for (int j = 0; j < 4; ++j) {
                float p0 = 0.f, p1 = 0.f;
                #pragma unroll
                for (int n = 0; n < 2; ++n) {
                    float v = fmaxf(acc[m][n][j] * WINV + bv2[n], 0.f);
                    p0 += v * w30[n];
                    p1 += v * w31[n];
                }
                #pragma unroll
                for (int msk = 1; msk < 16; msk <<= 1) {   // reduce over 16 lr-lanes
                    p0 += __shfl_xor(p0, msk);
                    p1 += __shfl_xor(p1, msk);
                }
                if (lr == 0) {
                    int rl = m * 16 + lk * 4 + j;          // 0..63
                    red[rl * 17 + wid * 2 + 0] = p0;
                    red[rl * 17 + wid * 2 + 1] = p1;
                }
            }
        }
        __syncthreads();
        if (t < 128) {   // one (row, comp) per thread; 8-way sum; ONE atomic each
            int rl = t >> 1, comp = t & 1;
            float v = 0.f;
            #pragma unroll
            for (int w = 0; w < 8; ++w)
                v += red[rl * 17 + w * 2 + comp];
            atomicAdd(&out[(size_t)(mBase + rl) * 2 + comp], v);   // 2 contenders
        }
    }
}

// ---------- launch ----------
extern "C" void kernel_launch(void* const* d_in, const int* in_sizes, int n_in,
                              void* d_out, int out_size, void* d_ws, size_t ws_size,
                              hipStream_t stream) {
    const float* x  = (const float*)d_in[0];
    const float* W1 = (const float*)d_in[1];
    const float* b1 = (const float*)d_in[2];
    const float* W2 = (const float*)d_in[3];
    const float* b2 = (const float*)d_in[4];
    const float* W3 = (const float*)d_in[5];
    const float* b3 = (const float*)d_in[6];
    const int*  pxs = (const int*)d_in[7];
    const int*  pys = (const int*)d_in[8];
    float* out = (float*)d_out;
    char* ws = (char*)d_ws;

    // ws layout (bytes): W1t 786,432 | W2t 262,144 | h1 25,690,112 |
    //                    x8 38,535,168 | pidx 401,408  (end 65,675,264)
    unsigned char* W1t  = (unsigned char*)(ws + 0);
    unsigned char* W2t  = (unsigned char*)(ws + 786432);
    unsigned char* h1   = (unsigned char*)(ws + 1048576);
    unsigned char* x8   = (unsigned char*)(ws + 26738688);
    int*           pidx = (int*)(ws + 65273856);

    hipFuncSetAttribute((const void*)gemm64,
                        hipFuncAttributeMaxDynamicSharedMemorySize, 81920);

    // xpose8 (+24 weight-prep blocks): x8, pidx, out-init, W1t/W2t
    xpose8<<<dim3(12, BATCH + 2), 512, 0, stream>>>(x, pxs, pys, b3, W1, W2,
                                                    W1t, W2t, x8, pidx, out);
    // GEMM1 (gathered A): h1 = relu(gather(x8)@W1t^T /64 + b1)
    gemm64<<<(MROWS / 64) * 2, 512, 81920, stream>>>(
        x8, W1t, b1, h1, nullptr, nullptr, pidx, K1, 0);
    // GEMM2 (+GEMM3 fold): out[0:2M) += relu(h1 @ W2t^T /64 + b2) @ W3
    gemm64<<<(MROWS / 64) * 2, 512, 81920, stream>>>(
        h1, W2t, b2, nullptr, W3, out, nullptr, HID, 1);
}

// Round 28
// 145.097 us; speedup vs baseline: 1.1899x; 1.1899x over previous
//
#include <hip/hip_runtime.h>
#include <hip/hip_bf16.h>

// ---------- types / helpers ----------
typedef __attribute__((ext_vector_type(4))) float f32x4;   // MFMA C/D frag
typedef __attribute__((ext_vector_type(4))) int   int4v;   // one 16B load
typedef __attribute__((ext_vector_type(8))) int   int8v;   // K=128 fp8 A/B frag (32B)

// float -> OCP e4m3fn byte (cold path: weight prep only)
__device__ __forceinline__ unsigned char f2fp8(float f) {
    unsigned char s = (__float_as_uint(f) >> 24) & 0x80;
    float a = fabsf(f);
    if (a >= 448.f) return s | 0x7E;
    if (a < 0.015625f) {                       // subnormal: step 2^-9
        int q = (int)(a * 512.0f + 0.5f);
        return s | (unsigned char)q;
    }
    unsigned int u = __float_as_uint(a);
    u += 0x0007FFFF + ((u >> 20) & 1);         // RNE to 3 mantissa bits (carry-safe)
    int e8 = (int)((u >> 23) & 0xFF) - 120;    // -127+7
    if (e8 >= 16) return s | 0x7E;
    return s | (unsigned char)((e8 << 3) | ((u >> 20) & 7));
}
__device__ __forceinline__ void gload_lds16(const void* g, void* l) {
    // async global->LDS, 16B/lane; LDS dest = wave-uniform base + lane*16 (linear!)
    // global SOURCE is per-lane -> gathered (indexed-row) staging is legal.
    __builtin_amdgcn_global_load_lds((const __attribute__((address_space(1))) void*)g,
                                     (__attribute__((address_space(3))) void*)l, 16, 0, 0);
}

// ---------- constants ----------
#define BATCH 256
#define CHAN  768
#define HW    196
#define SPS   196
#define HID   512
#define MROWS 50176   // BATCH*SPS
#define K1    1536    // 2*CHAN
#define WSCL  64.0f           // weights pre-scaled by 64 (e4m3 subnormal dodge)
#define WINV  0.015625f       // 1/64 applied after each GEMM
#define SC1   0x7F7F7F7F      // E8M0 scale 1.0 in every byte
#define GPITCH 198            // xpose8 LDS row pitch (floats)

// R28 = R26 verbatim (proven 145.7us twice).  R27's grid-fold of weight-prep into
// 24 blocks serialized it (~21 iters/thread -> 125us tail) -> reverted to the
// 1024-block standalone prep.  R25's single-kernel fusion also reverted earlier.
// Structure: prep_weights | xpose8 (x8+pidx+out-init) | gemm64 x2 (GEMM1 gathered-A,
// GEMM2+GEMM3-fold).  gemm64: BM=64, BN=256, BK=128, 8 waves, acc[4][2] (no spill),
// 80KB LDS -> 2 blocks/CU, issue-early dbuf, 16B ^(r&7) swizzle.

// ---------- merged weight prep: coalesced reads, W1/W2 -> [N][K] fp8 of w*64 ----------
__global__ __launch_bounds__(256) void prep_weights(const float* __restrict__ W1,
                                                    const float* __restrict__ W2,
                                                    unsigned char* __restrict__ W1t,
                                                    unsigned char* __restrict__ W2t) {
    const int G1 = K1 * (HID / 4);                 // 196,608 float4-groups for W1
    int idx = blockIdx.x * 256 + threadIdx.x;      // grid = (G1+G2)/256 = 1024 exactly
    if (idx < G1) {
        int k = idx >> 7, g = idx & 127;           // 128 groups per k-row
        float4 v = *(const float4*)(W1 + (size_t)k * HID + g * 4);   // coalesced 16B
        W1t[(size_t)(g * 4 + 0) * K1 + k] = f2fp8(v.x * WSCL);
        W1t[(size_t)(g * 4 + 1) * K1 + k] = f2fp8(v.y * WSCL);
        W1t[(size_t)(g * 4 + 2) * K1 + k] = f2fp8(v.z * WSCL);
        W1t[(size_t)(g * 4 + 3) * K1 + k] = f2fp8(v.w * WSCL);
    } else {
        int i = idx - G1;                          // < 512*128
        int k = i >> 7, g = i & 127;
        float4 v = *(const float4*)(W2 + (size_t)k * HID + g * 4);
        W2t[(size_t)(g * 4 + 0) * HID + k] = f2fp8(v.x * WSCL);
        W2t[(size_t)(g * 4 + 1) * HID + k] = f2fp8(v.y * WSCL);
        W2t[(size_t)(g * 4 + 2) * HID + k] = f2fp8(v.z * WSCL);
        W2t[(size_t)(g * 4 + 3) * HID + k] = f2fp8(v.w * WSCL);
    }
}

// ---------- xpose8: x[b][c][pos] fp32 -> x8[b][pos][c] fp8; pidx; deltaxy; pred=b3 ----------
__global__ __launch_bounds__(512) void xpose8(const float* __restrict__ x,
                                              const int* __restrict__ pxs,
                                              const int* __restrict__ pys,
                                              const float* __restrict__ b3,
                                              unsigned char* __restrict__ x8,
                                              int* __restrict__ pidx,
                                              float* __restrict__ out) {
    __shared__ float lds[64 * GPITCH];   // 50,688 B -> 3 blocks/CU
    int chunk = blockIdx.x;           // 0..11 (64-channel chunk)
    int b     = blockIdx.y;           // 0..255
    int c0 = chunk * 64;
    const float4* xb4 = (const float4*)(x + ((size_t)b * CHAN + c0) * HW);  // 16B-aligned
    for (int vt = threadIdx.x; vt < 64 * 49; vt += 512) {    // 64 rows x 49 float4
        float4 v = xb4[vt];
        int j = vt / 49, p4 = vt - j * 49;
        float* dst = &lds[j * GPITCH + p4 * 4];              // 8B-aligned (GPITCH even)
        *(float2*)(dst + 0) = make_float2(v.x, v.y);
        *(float2*)(dst + 2) = make_float2(v.z, v.w);
    }
    if (chunk == 0) {                 // per-batch: pred=b3, deltaxy, pidx
        float b30 = b3[0], b31 = b3[1];
        for (int i = threadIdx.x; i < SPS * 2; i += 512) {
            int idx = b * SPS * 2 + i;
            out[idx] = (i & 1) ? b31 : b30;                  // pred init (GEMM2 atomics add)
            out[MROWS * 2 + idx] = (float)(pxs[idx] - pys[idx]) + 13.0f;  // (H-1)=13
        }
        for (int s = threadIdx.x; s < SPS; s += 512) {
            int base = (b * SPS + s) * 2;
            int ix = pxs[base] * 14 + pxs[base + 1];
            int iy = pys[base] * 14 + pys[base + 1];
            pidx[(b * SPS + s) * 2 + 0] = b * HW + ix;
            pidx[(b * SPS + s) * 2 + 1] = b * HW + iy;
        }
    }
    __syncthreads();
    int wid = threadIdx.x >> 6, lane = threadIdx.x & 63;
    int g = lane >> 4;                // pos-offset within the 4-pos pack
    int cq = (lane & 15) * 4;         // channel quad
    const float* lx = lds + cq * GPITCH;
    // p = 4*wid + 32k + g covers 0..195 exactly once
    for (int pb = wid * 4; pb < HW; pb += 32) {
        int p = pb + g;
        unsigned int u = 0;
        u = __builtin_amdgcn_cvt_pk_fp8_f32(lx[p],              lx[GPITCH + p],     u, false);
        u = __builtin_amdgcn_cvt_pk_fp8_f32(lx[2 * GPITCH + p], lx[3 * GPITCH + p], u, true);
        *(unsigned int*)(x8 + ((size_t)b * HW + p) * CHAN + c0 + cq) = u;  // 64B/16-lane grp
    }
}

// ---------- 64x256 MX-fp8 GEMM, spill-free; optional gathered-A (R24, proven) ----------
// C = relu((A @ Bt^T)/64 + bias) -> fp8 (predMode=0), or pred-fold (predMode=1).
// pidx != nullptr: A rows are gathered from x8 (row pidx[r*2+(kt>=6)], 768B rows).
// Grid 1-D: nHalf = bid&1 (cols 0-255 / 256-511), mChunk = bid>>1.
__global__ __launch_bounds__(512, 2)
void gemm64(const unsigned char* __restrict__ A,
            const unsigned char* __restrict__ Bt,
            const float* __restrict__ bias,
            unsigned char* __restrict__ C,
            const float* __restrict__ W3,
            float* __restrict__ out,
            const int* __restrict__ pidx,
            int Kd, int predMode) {
    extern __shared__ char smem[];    // 81920 B: [A0 8K | A1 8K | B0 32K | B1 32K]
    const int t = threadIdx.x;
    const int wid = t >> 6, lane = t & 63;
    const int lr = lane & 15, lk = lane >> 4;
    const int mBase = (blockIdx.x >> 1) * 64;
    const int nBase = (blockIdx.x & 1) * 256;
    const int nK = Kd >> 7;           // BK=128
    f32x4 acc[4][2] = {};             // 32 regs; live ~90 <= 128-reg budget: no spill

    // gathered-A row ids for this thread's fixed staging row (t>>3), L2-hot
    int prx = 0, pry = 0;
    if (pidx) {
        int gr = mBase + (t >> 3);
        prx = pidx[gr * 2 + 0];
        pry = pidx[gr * 2 + 1];
    }

    auto stage = [&](int buf, int kt) {
        char* Ab = smem + buf * 8192;
        char* Bb = smem + 16384 + buf * 32768;
        {                                         // A: 512 units = 64 rows x 128B
            int row = t >> 3, cs = (t & 7) ^ (row & 7);
            const unsigned char* asrc;
            if (pidx) {                           // gathered from x8 (768B rows)
                int srcRow = (kt < 6) ? prx : pry;
                int kk = (kt < 6) ? kt : kt - 6;
                asrc = A + (size_t)srcRow * CHAN + kk * 128 + cs * 16;
            } else {
                asrc = A + (size_t)(mBase + row) * Kd + kt * 128 + cs * 16;
            }
            gload_lds16(asrc, Ab + t * 16);
        }
        #pragma unroll
        for (int i = 0; i < 4; ++i) {             // B: 2048 units = 256 rows x 128B
            int lin = i * 512 + t, row = lin >> 3, cs = (lin & 7) ^ (row & 7);
            gload_lds16(Bt + (size_t)(nBase + row) * Kd + kt * 128 + cs * 16,
                        Bb + lin * 16);
        }
    };
    auto frag128 = [&](const char* rowp, int r) -> int8v {   // swizzled 32B frag, 128B row
        union { int4v h[2]; int8v v; } u;
        u.h[0] = *(const int4v*)(rowp + (((2 * lk + 0) ^ (r & 7)) * 16));
        u.h[1] = *(const int4v*)(rowp + (((2 * lk + 1) ^ (r & 7)) * 16));
        return u.v;
    };
    auto compute = [&](int buf) {
        const char* Ab = smem + buf * 8192;
        const char* Bb = smem + 16384 + buf * 32768;
        int8v af[4];
        #pragma unroll
        for (int m = 0; m < 4; ++m) {             // all waves share rows 0..63 (broadcast)
            int r = m * 16 + lr;
            af[m] = frag128(Ab + r * 128, r);
        }
        #pragma unroll
        for (int n = 0; n < 2; ++n) {             // one B frag live at a time
            int r = wid * 32 + n * 16 + lr;
            int8v bf = frag128(Bb + r * 128, r);
            #pragma unroll
            for (int m = 0; m < 4; ++m)
                acc[m][n] = __builtin_amdgcn_mfma_scale_f32_16x16x128_f8f6f4(
                    af[m], bf, acc[m][n], 0, 0, 0, SC1, 0, SC1);
        }
    };

    stage(0, 0);
    __syncthreads();
    int cur = 0;
    for (int kt = 0; kt < nK; ++kt) {
        if (kt + 1 < nK) stage(cur ^ 1, kt + 1);   // flies under compute(kt)
        compute(cur);
        __syncthreads();
        cur ^= 1;
    }

    if (!predMode) {
        // h1 = relu(acc/64 + b1) -> fp8 global.  C row=lk*4+j, col=lane&15 (verified)
        #pragma unroll
        for (int n = 0; n < 2; ++n) {
            int c = nBase + wid * 32 + n * 16 + lr;
            float bv = bias[c];
            #pragma unroll
            for (int m = 0; m < 4; ++m) {
                int r0 = mBase + m * 16 + lk * 4;
                float v0 = fmaxf(acc[m][n][0] * WINV + bv, 0.f);
                float v1 = fmaxf(acc[m][n][1] * WINV + bv, 0.f);
                float v2 = fmaxf(acc[m][n][2] * WINV + bv, 0.f);
                float v3 = fmaxf(acc[m][n][3] * WINV + bv, 0.f);
                unsigned int u = __builtin_amdgcn_cvt_pk_fp8_f32(v0, v1, 0u, false);
                u = __builtin_amdgcn_cvt_pk_fp8_f32(v2, v3, u, true);
                #pragma unroll
                for (int j = 0; j < 4; ++j)
                    C[(size_t)(r0 + j) * HID + c] = (unsigned char)((u >> (8 * j)) & 0xff);
            }
        }
    } else {
        // pred fold: pred[r] += sum_c relu(acc/64+b2)[r][c] * W3[c][:]
        float* red = (float*)smem;    // [64][17] f32 = 4.4KB over dead A0/A1
        float bv2[2], w30[2], w31[2];
        #pragma unroll
        for (int n = 0; n < 2; ++n) {
            int c = nBase + wid * 32 + n * 16 + lr;
            bv2[n] = bias[c];
            w30[n] = W3[c * 2];
            w31[n] = W3[c * 2 + 1];
        }
        __syncthreads();              // all LDS reads of A/B done before red overwrite
        #pragma unroll
        for (int m = 0; m < 4; ++m) {
            #pragma unroll
            for (int j = 0; j < 4; ++j) {
                float p0 = 0.f, p1 = 0.f;
                #pragma unroll
                for (int n = 0; n < 2; ++n) {
                    float v = fmaxf(acc[m][n][j] * WINV + bv2[n], 0.f);
                    p0 += v * w30[n];
                    p1 += v * w31[n];
                }
                #pragma unroll
                for (int msk = 1; msk < 16; msk <<= 1) {   // reduce over 16 lr-lanes
                    p0 += __shfl_xor(p0, msk);
                    p1 += __shfl_xor(p1, msk);
                }
                if (lr == 0) {
                    int rl = m * 16 + lk * 4 + j;          // 0..63
                    red[rl * 17 + wid * 2 + 0] = p0;
                    red[rl * 17 + wid * 2 + 1] = p1;
                }
            }
        }
        __syncthreads();
        if (t < 128) {   // one (row, comp) per thread; 8-way sum; ONE atomic each
            int rl = t >> 1, comp = t & 1;
            float v = 0.f;
            #pragma unroll
            for (int w = 0; w < 8; ++w)
                v += red[rl * 17 + w * 2 + comp];
            atomicAdd(&out[(size_t)(mBase + rl) * 2 + comp], v);   // 2 contenders
        }
    }
}

// ---------- launch ----------
extern "C" void kernel_launch(void* const* d_in, const int* in_sizes, int n_in,
                              void* d_out, int out_size, void* d_ws, size_t ws_size,
                              hipStream_t stream) {
    const float* x  = (const float*)d_in[0];
    const float* W1 = (const float*)d_in[1];
    const float* b1 = (const float*)d_in[2];
    const float* W2 = (const float*)d_in[3];
    const float* b2 = (const float*)d_in[4];
    const float* W3 = (const float*)d_in[5];
    const float* b3 = (const float*)d_in[6];
    const int*  pxs = (const int*)d_in[7];
    const int*  pys = (const int*)d_in[8];
    float* out = (float*)d_out;
    char* ws = (char*)d_ws;

    // ws layout (bytes): W1t 786,432 | W2t 262,144 | h1 25,690,112 |
    //                    x8 38,535,168 | pidx 401,408  (end 65,675,264)
    unsigned char* W1t  = (unsigned char*)(ws + 0);
    unsigned char* W2t  = (unsigned char*)(ws + 786432);
    unsigned char* h1   = (unsigned char*)(ws + 1048576);
    unsigned char* x8   = (unsigned char*)(ws + 26738688);
    int*           pidx = (int*)(ws + 65273856);

    hipFuncSetAttribute((const void*)gemm64,
                        hipFuncAttributeMaxDynamicSharedMemorySize, 81920);

    // merged coalesced weight prep: (K1*128 + 512*128) / 256 = 1024 blocks exactly
    prep_weights<<<1024, 256, 0, stream>>>(W1, W2, W1t, W2t);
    // xpose8: x8 + pidx + out-init (pred=b3, deltaxy)
    xpose8<<<dim3(12, BATCH), 512, 0, stream>>>(x, pxs, pys, b3, x8, pidx, out);
    // GEMM1 (gathered A): h1 = relu(gather(x8)@W1t^T /64 + b1)
    gemm64<<<(MROWS / 64) * 2, 512, 81920, stream>>>(
        x8, W1t, b1, h1, nullptr, nullptr, pidx, K1, 0);
    // GEMM2 (+GEMM3 fold): out[0:2M) += relu(h1 @ W2t^T /64 + b2) @ W3
    gemm64<<<(MROWS / 64) * 2, 512, 81920, stream>>>(
        h1, W2t, b2, nullptr, W3, out, nullptr, HID, 1);
}